// Round 14
// baseline (135.285 us; speedup 1.0000x reference)
//
#include <hip/hip_runtime.h>

#define EPS 1e-6f

constexpr int Bn = 4096;   // batch rows
constexpr int Dn = 1024;   // feature dim
constexpr int Kn = 4096;   // codebook entries

typedef __attribute__((ext_vector_type(4))) float f32x4;      // MFMA accumulator
typedef __attribute__((ext_vector_type(4))) int   i32x4;      // 16B LDS/global read
typedef __attribute__((ext_vector_type(8))) int   i32x8;      // 32B MX fragment

// 'hi' operand of cvt_pk_fp8 must be an immediate — two literal wrappers.
__device__ inline int pk_fp8_lo(float a, float b, int old) {
    return __builtin_amdgcn_cvt_pk_fp8_f32(a, b, old, false);  // HW RNE e4m3
}
__device__ inline int pk_fp8_hi(float a, float b, int old) {
    return __builtin_amdgcn_cvt_pk_fp8_f32(a, b, old, true);
}

// pack candidate k (12 bits) into low mantissa of positive score s.
__device__ inline float packcand(float s, int k) {
    unsigned b = __float_as_uint(fmaxf(s, 0.5f));
    return __uint_as_float((b & 0xFFFFF000u) | (unsigned)k);
}

// xf8/wf8 are stored PRE-PERMUTED for the MX gemm: within each 128-B k-block,
// byte d sits at pi(d) = ((d>>3)&3)*32 + ((d>>5)&3)*8 + (d&7)  (q-major MFMA
// fragment order; A and B share it, so the instruction's lane->k map cancels
// — proven by R1's absmax=0.0), XORed with the bank swizzle ((row&7)<<4) so
// LDS linear-row copies read conflict-free AND each lane's 32-B fragment is
// contiguous in global memory (A-direct-to-register).
__device__ inline int permoff(int dc, int r) {
    int db = dc & 127;
    int pcol = ((db >> 3) & 3) * 32 + ((db >> 5) & 3) * 8 + (db & 7);
    return (dc & ~127) + (pcol ^ ((r & 7) << 4));
}

// async global->LDS, 16 B per lane; LDS dst = wave-uniform base + lane*16
__device__ inline void gload16(const unsigned char* g, unsigned char* l) {
    __builtin_amdgcn_global_load_lds(
        (const __attribute__((address_space(1))) void*)g,
        (__attribute__((address_space(3))) void*)l, 16, 0, 0);
}

// ---- fused prep: phase A (bid<2048) x->fp8(permuted) + row stats;        -
// ----             phase B (bid>=2048) w transpose (fp32 + fp8 permuted)   -
__global__ __launch_bounds__(256) void som_prep(
    const float* __restrict__ x, const float* __restrict__ w,
    unsigned char* __restrict__ xf8, float* __restrict__ rrow,
    float* __restrict__ wtf, unsigned char* __restrict__ wf8,
    float* __restrict__ cpart) {
    __shared__ float t[64][65];
    __shared__ float cp[4][64];
    __shared__ float red[8];
    const int tid = threadIdx.x;
    const int bid = blockIdx.x;
    if (bid < 2048) {
        const int lane = tid & 63, wid = tid >> 6;
        size_t i = (size_t)bid * 256 + tid;          // 8 elems / thread
        const int row = (int)(i >> 7);
        const int d0 = (int)(i & 127) * 8;
        const float4* p = (const float4*)x;
        float4 a = p[i * 2], b = p[i * 2 + 1];
        int lo = pk_fp8_lo(a.x, a.y, 0); lo = pk_fp8_hi(a.z, a.w, lo);
        int hi = pk_fp8_lo(b.x, b.y, 0); hi = pk_fp8_hi(b.z, b.w, hi);
        *(int2*)(xf8 + (size_t)row * Dn + permoff(d0, row)) = make_int2(lo, hi);
        float s2 = a.x*a.x + a.y*a.y + a.z*a.z + a.w*a.w
                 + b.x*b.x + b.y*b.y + b.z*b.z + b.w*b.w;
        float s1 = a.x + a.y + a.z + a.w + b.x + b.y + b.z + b.w;
        #pragma unroll
        for (int off = 1; off < 64; off <<= 1) {
            s2 += __shfl_xor(s2, off);
            s1 += __shfl_xor(s1, off);
        }
        if (lane == 0) { red[wid] = s2; red[4 + wid] = s1; }
        __syncthreads();
        if (tid == 0)
            rrow[bid * 2] = (red[0] + red[1])
                + 2.f * EPS * (red[4] + red[5]) + (float)Dn * EPS * EPS;
        if (tid == 128)
            rrow[bid * 2 + 1] = (red[2] + red[3])
                + 2.f * EPS * (red[6] + red[7]) + (float)Dn * EPS * EPS;
    } else {
        const int tb = bid - 2048;
        const int kb = tb & 63, db = tb >> 6;        // 64 k-blocks x 16 d-blocks
        const int k0 = kb * 64, d0 = db * 64;
        const int l16 = tid & 15, g16 = tid >> 4;    // 16 lanes x 16 groups
        #pragma unroll
        for (int i = 0; i < 4; ++i) {
            int r = i * 16 + g16;                    // d-row within tile
            float4 v = *(const float4*)&w[(size_t)(d0 + r) * Kn + k0 + l16 * 4];
            t[r][l16 * 4 + 0] = v.x; t[r][l16 * 4 + 1] = v.y;
            t[r][l16 * 4 + 2] = v.z; t[r][l16 * 4 + 3] = v.w;
        }
        __syncthreads();
        #pragma unroll
        for (int i = 0; i < 4; ++i) {
            int kr = i * 16 + g16;                   // k-row within tile
            float4 v;
            v.x = t[l16 * 4 + 0][kr]; v.y = t[l16 * 4 + 1][kr];
            v.z = t[l16 * 4 + 2][kr]; v.w = t[l16 * 4 + 3][kr];
            *(float4*)&wtf[(size_t)(k0 + kr) * Dn + d0 + l16 * 4] = v;
            int pk = pk_fp8_lo(v.x, v.y, 0); pk = pk_fp8_hi(v.z, v.w, pk);
            const int krow = k0 + kr;
            *(unsigned int*)&wf8[(size_t)krow * Dn + permoff(d0 + l16 * 4, krow)] =
                (unsigned int)pk;                    // bytes 0..3 = fp8(x,y,z,w)
        }
        // column-stat partial over this block's 64 d: sum (w^2 - 2 eps w)
        const int tx = tid & 63, ty = tid >> 6;
        float cs = 0.f;
        #pragma unroll
        for (int j = 0; j < 16; ++j) {
            float v = t[ty * 16 + j][tx];
            cs = fmaf(v, v - 2.f * EPS, cs);
        }
        cp[ty][tx] = cs;
        __syncthreads();
        if (ty == 0)
            cpart[(size_t)db * Kn + k0 + tx] = cp[0][tx] + cp[1][tx] + cp[2][tx] + cp[3][tx];
    }
}

// ---- MX-fp8 MFMA screen GEMM: A direct-to-register + B LDS double-buffer,
// R10's __syncthreads schedule (true compiler fence + full drain — immune to
// the counted-vmcnt unsoundness that broke R13: extra uncounted A-loads in
// the vmem stream invalidated the "oldest 8 = B tile" bookkeeping, and raw
// s_barrier is not a compiler fence). A bytes are provably identical to the
// old LDS copy (LDS row r, col c == global row rowBase+r, col it*128+c).
// LDS 32 KB -> 3 blocks/CU; ds_read per iter halves (8 b128 vs 16).
__global__ __launch_bounds__(256, 3) void som_gemm_mx(
    const unsigned char* __restrict__ xf8, const unsigned char* __restrict__ wf8,
    const float* __restrict__ cpart, float* __restrict__ pval) {
    __shared__ __align__(16) unsigned char Bs[2][128 * 128];
    const int tid = threadIdx.x;
    const int lane = tid & 63;
    const int wid = tid >> 6;
    const int wm = wid >> 1, wn = wid & 1;    // 2x2 waves of 64x64
    const int f = blockIdx.x;
    const int xcd = f & 7;
    const int ib = f >> 3;
    const int rb = xcd * 4 + (ib & 3);
    const int cb = ib >> 2;
    const int rowBase = rb * 128, colBase = cb * 128;

    // B staging: wave issue i covers rows [wid*8 + i*32, +8); lane l -> row
    // +(l>>3), byte (l&7)*16; 4 gload_lds per wave per tile.
    const unsigned char* gB0 = wf8 + (size_t)(colBase + wid * 8 + (lane >> 3)) * Dn + (lane & 7) * 16;
    const int lOff = (wid * 8) * 128;

    f32x4 acc[4][4] = {};

    // fragment geometry: lane (row lane&15, quad q=lane>>4) reads its 32-B
    // fragment as two 16-B slots at XOR-decoded columns.
    const int arow = wm * 64 + (lane & 15);
    const int brow = wn * 64 + (lane & 15);
    const int q32 = (lane >> 4) * 32;
    const int aL = q32 ^ ((arow & 7) << 4), aH = (q32 + 16) ^ ((arow & 7) << 4);
    const int bL = q32 ^ ((brow & 7) << 4), bH = (q32 + 16) ^ ((brow & 7) << 4);

    // A-fragment global base rows ((rowBase+arow+i*16)&7 == arow&7 since
    // rowBase%8==0 and 16%8==0 -> aL/aH decode identically to the LDS path)
    const unsigned char* gAf[4];
    #pragma unroll
    for (int i = 0; i < 4; ++i)
        gAf[i] = xf8 + (size_t)(rowBase + arow + i * 16) * Dn;

    #pragma unroll
    for (int i = 0; i < 4; ++i)               // prologue: stage B tile 0
        gload16(gB0 + (size_t)i * 32 * Dn, &Bs[0][lOff + i * 32 * 128]);
    __syncthreads();                          // full drain: buf 0 ready

    int cur = 0;
    for (int it = 0; it < 8; ++it) {
        if (it < 7) {                         // stage B[it+1] first: loads fly
            const int d0n = (it + 1) * 128;   // under this iter's compute
            #pragma unroll
            for (int i = 0; i < 4; ++i)
                gload16(gB0 + (size_t)i * 32 * Dn + d0n, &Bs[cur ^ 1][lOff + i * 32 * 128]);
        }
        const int d0c = it * 128;
        i32x8 af[4];
        #pragma unroll
        for (int i = 0; i < 4; ++i) {         // A fragments straight from L2
            i32x4 lo = *(const i32x4*)(gAf[i] + d0c + aL);
            i32x4 hi = *(const i32x4*)(gAf[i] + d0c + aH);
            af[i] = __builtin_shufflevector(lo, hi, 0, 1, 2, 3, 4, 5, 6, 7);
        }
        const unsigned char* cB = Bs[cur];
        #pragma unroll
        for (int j = 0; j < 4; ++j) {
            i32x4 lo = *(const i32x4*)&cB[(brow + j * 16) * 128 + bL];
            i32x4 hi = *(const i32x4*)&cB[(brow + j * 16) * 128 + bH];
            i32x8 bf = __builtin_shufflevector(lo, hi, 0, 1, 2, 3, 4, 5, 6, 7);
            #pragma unroll
            for (int i = 0; i < 4; ++i)
                asm("v_mfma_f32_16x16x128_f8f6f4 %0, %1, %2, %0"
                    : "+v"(acc[i][j]) : "v"(af[i]), "v"(bf));
        }
        __syncthreads();                      // reads done + next buf landed
        cur ^= 1;
    }

    // epilogue: c[k] from cpart, then packed top-2 per (row, 64-col group)
    const int cn = lane & 15, q = lane >> 4;
    const int nbase = colBase + wn * 64;
    float cv[4];
    #pragma unroll
    for (int j = 0; j < 4; ++j) {
        float s = 0.f;
        #pragma unroll
        for (int db = 0; db < 16; ++db)
            s += cpart[(size_t)db * Kn + nbase + j * 16 + cn];
        cv[j] = s;
    }
    #pragma unroll
    for (int i = 0; i < 4; ++i) {
        #pragma unroll
        for (int rg = 0; rg < 4; ++rg) {
            float p1 = 3.4e38f, p2 = 3.4e38f;
            #pragma unroll
            for (int j = 0; j < 4; ++j) {
                float p = packcand(fmaf(-2.f, acc[i][j][rg], cv[j]),
                                   nbase + j * 16 + cn);
                float lo = fminf(p1, p), hi = fmaxf(p1, p);
                p1 = lo; p2 = fminf(p2, hi);
            }
            #pragma unroll
            for (int off = 1; off < 16; off <<= 1) {
                float o1 = __shfl_xor(p1, off);
                float o2 = __shfl_xor(p2, off);
                float lo = fminf(p1, o1), hi = fmaxf(p1, o1);
                p1 = lo; p2 = fminf(hi, fminf(p2, o2));
            }
            if (cn == 0) {
                int mrow = rowBase + wm * 64 + i * 16 + q * 4 + rg;
                size_t e = (size_t)mrow * 128 + cb * 4 + wn * 2;
                pval[e] = p1; pval[e + 1] = p2;
            }
        }
    }
}

// ---- finalize: exact fp32 rescore of candidates in margin (R11-exact) ----
__global__ __launch_bounds__(256) void som_finalize(
    const float* __restrict__ x, const float* __restrict__ wtf,
    const float* __restrict__ cpart, const float* __restrict__ loc,
    const float* __restrict__ pval, const float* __restrict__ rrow,
    float* __restrict__ dist, float* __restrict__ out) {
    const int lane = threadIdx.x & 63;
    const int row = blockIdx.x * 4 + (threadIdx.x >> 6);

    const float4* xr = (const float4*)(x + (size_t)row * Dn);
    float4 xv[4];
    #pragma unroll
    for (int j = 0; j < 4; ++j) xv[j] = xr[lane * 4 + j];
    const float rrv = rrow[row];

    float v0 = pval[(size_t)row * 128 + lane];
    float v1 = pval[(size_t)row * 128 + 64 + lane];
    float g = fminf(v0, v1);
    #pragma unroll
    for (int off = 1; off < 64; off <<= 1) g = fminf(g, __shfl_xor(g, off));
    const float thr = g + 30.0f;  // fp8 screen noise (sigma~2.7) + pack error
    unsigned long long m0 = __ballot(v0 <= thr);
    unsigned long long m1 = __ballot(v1 <= thr);

    float bestd2 = 3.4e38f; int bestk = 0x7fffffff;
    #pragma unroll
    for (int slot = 0; slot < 2; ++slot) {
        unsigned long long m = slot ? m1 : m0;
        float vs = slot ? v1 : v0;
        while (m) {
            int src = __builtin_ctzll(m); m &= m - 1;
            int k = ((int)__float_as_uint(__shfl(vs, src))) & 0xFFF;
            const float4* wr = (const float4*)(wtf + (size_t)k * Dn);
            float pa = (lane < 16) ? cpart[(size_t)lane * Kn + k] : 0.f;
            float da = 0.f;
            #pragma unroll
            for (int j = 0; j < 4; ++j) {
                float4 wv = wr[lane * 4 + j];
                da += xv[j].x * wv.x + xv[j].y * wv.y + xv[j].z * wv.z + xv[j].w * wv.w;
            }
            pa -= 2.f * da;
            #pragma unroll
            for (int off = 1; off < 64; off <<= 1) pa += __shfl_xor(pa, off);
            float d2 = rrv + pa;
            if (d2 < bestd2 || (d2 == bestd2 && k < bestk)) { bestd2 = d2; bestk = k; }
        }
    }
    if (lane == 0) {
        out[2 * row]     = loc[2 * bestk];
        out[2 * row + 1] = loc[2 * bestk + 1];
        out[8193 + row]  = (float)bestk;
        dist[row]        = sqrtf(fmaxf(bestd2, 0.f));
    }
}

// ---- loss: single block reduces the 4096 per-row distances ----------------
__global__ __launch_bounds__(256) void som_loss(const float* __restrict__ dist,
                                                float* __restrict__ out) {
    __shared__ float red[4];
    const int tid = threadIdx.x;
    const int lane = tid & 63, wid = tid >> 6;
    const float4* p = (const float4*)dist;
    float s = 0.f;
    #pragma unroll
    for (int j = 0; j < 4; ++j) {
        float4 v = p[tid + j * 256];
        s += v.x + v.y + v.z + v.w;
    }
    #pragma unroll
    for (int off = 1; off < 64; off <<= 1) s += __shfl_xor(s, off);
    if (lane == 0) red[wid] = s;
    __syncthreads();
    if (tid == 0)
        out[8192] = (red[0] + red[1] + red[2] + red[3]) * (1.0f / (float)Bn);
}

extern "C" void kernel_launch(void* const* d_in, const int* in_sizes, int n_in,
                              void* d_out, int out_size, void* d_ws, size_t ws_size,
                              hipStream_t stream) {
    const float* x   = (const float*)d_in[0];   // [B, D]
    const float* w   = (const float*)d_in[1];   // [D, K]
    const float* loc = (const float*)d_in[2];   // [K, 2]
    float* out = (float*)d_out;

    float* rrow = (float*)d_ws;                            // 16 KB  [B]
    float* wtf  = rrow + Bn;                               // 16 MB  [K][D] fp32
    unsigned char* wf8 = (unsigned char*)(wtf + (size_t)Kn * Dn);  // 4 MB
    unsigned char* xf8 = wf8 + (size_t)Kn * Dn;            // 4 MB
    float* pval = (float*)(xf8 + (size_t)Bn * Dn);         // 2 MB packed top-2
    float* cpart = pval + (size_t)Bn * 128;                // 256 KB [16][K]
    float* dist  = cpart + 16 * Kn;                        // 16 KB  [B]

    som_prep<<<3072, 256, 0, stream>>>(x, w, xf8, rrow, wtf, wf8, cpart);
    som_gemm_mx<<<1024, 256, 0, stream>>>(xf8, wf8, cpart, pval);
    som_finalize<<<Bn / 4, 256, 0, stream>>>(x, wtf, cpart, loc, pval, rrow, dist, out);
    som_loss<<<1, 256, 0, stream>>>(dist, out);
}

// Round 15
// 131.197 us; speedup vs baseline: 1.0312x; 1.0312x over previous
//
#include <hip/hip_runtime.h>

#define EPS 1e-6f

constexpr int Bn = 4096;   // batch rows
constexpr int Dn = 1024;   // feature dim
constexpr int Kn = 4096;   // codebook entries

typedef __attribute__((ext_vector_type(4))) float f32x4;      // MFMA accumulator
typedef __attribute__((ext_vector_type(4))) int   i32x4;      // 16B LDS read
typedef __attribute__((ext_vector_type(8))) int   i32x8;      // 32B MX fragment

// 'hi' operand of cvt_pk_fp8 must be an immediate — two literal wrappers.
__device__ inline int pk_fp8_lo(float a, float b, int old) {
    return __builtin_amdgcn_cvt_pk_fp8_f32(a, b, old, false);  // HW RNE e4m3
}
__device__ inline int pk_fp8_hi(float a, float b, int old) {
    return __builtin_amdgcn_cvt_pk_fp8_f32(a, b, old, true);
}

// pack candidate k (12 bits) into low mantissa of positive score s.
__device__ inline float packcand(float s, int k) {
    unsigned b = __float_as_uint(fmaxf(s, 0.5f));
    return __uint_as_float((b & 0xFFFFF000u) | (unsigned)k);
}

// xf8/wf8 are stored PRE-PERMUTED for the MX gemm: within each 128-B k-block,
// byte d sits at pi(d) = ((d>>3)&3)*32 + ((d>>5)&3)*8 + (d&7)  (q-major MFMA
// fragment order; A and B share it, so the instruction's lane->k map cancels
// — proven by R1's absmax=0.0), XORed with the bank swizzle ((row&7)<<4) so
// the gemm's linear-row LDS (global_load_lds, no pad) reads conflict-free.
__device__ inline int permoff(int dc, int r) {
    int db = dc & 127;
    int pcol = ((db >> 3) & 3) * 32 + ((db >> 5) & 3) * 8 + (db & 7);
    return (dc & ~127) + (pcol ^ ((r & 7) << 4));
}

// async global->LDS, 16 B per lane; LDS dst = wave-uniform base + lane*16
__device__ inline void gload16(const unsigned char* g, unsigned char* l) {
    __builtin_amdgcn_global_load_lds(
        (const __attribute__((address_space(1))) void*)g,
        (__attribute__((address_space(3))) void*)l, 16, 0, 0);
}

// ---- fused prep: phase A (bid<2048) x->fp8(permuted) + row stats;        -
// ----             phase B (bid>=2048) w transpose (fp32 + fp8 permuted)   -
__global__ __launch_bounds__(256) void som_prep(
    const float* __restrict__ x, const float* __restrict__ w,
    unsigned char* __restrict__ xf8, float* __restrict__ rrow,
    float* __restrict__ wtf, unsigned char* __restrict__ wf8,
    float* __restrict__ cpart) {
    __shared__ float t[64][65];
    __shared__ float cp[4][64];
    __shared__ float red[8];
    const int tid = threadIdx.x;
    const int bid = blockIdx.x;
    if (bid < 2048) {
        const int lane = tid & 63, wid = tid >> 6;
        size_t i = (size_t)bid * 256 + tid;          // 8 elems / thread
        const int row = (int)(i >> 7);
        const int d0 = (int)(i & 127) * 8;
        const float4* p = (const float4*)x;
        float4 a = p[i * 2], b = p[i * 2 + 1];
        int lo = pk_fp8_lo(a.x, a.y, 0); lo = pk_fp8_hi(a.z, a.w, lo);
        int hi = pk_fp8_lo(b.x, b.y, 0); hi = pk_fp8_hi(b.z, b.w, hi);
        *(int2*)(xf8 + (size_t)row * Dn + permoff(d0, row)) = make_int2(lo, hi);
        float s2 = a.x*a.x + a.y*a.y + a.z*a.z + a.w*a.w
                 + b.x*b.x + b.y*b.y + b.z*b.z + b.w*b.w;
        float s1 = a.x + a.y + a.z + a.w + b.x + b.y + b.z + b.w;
        #pragma unroll
        for (int off = 1; off < 64; off <<= 1) {
            s2 += __shfl_xor(s2, off);
            s1 += __shfl_xor(s1, off);
        }
        if (lane == 0) { red[wid] = s2; red[4 + wid] = s1; }
        __syncthreads();
        if (tid == 0)
            rrow[bid * 2] = (red[0] + red[1])
                + 2.f * EPS * (red[4] + red[5]) + (float)Dn * EPS * EPS;
        if (tid == 128)
            rrow[bid * 2 + 1] = (red[2] + red[3])
                + 2.f * EPS * (red[6] + red[7]) + (float)Dn * EPS * EPS;
    } else {
        const int tb = bid - 2048;
        const int kb = tb & 63, db = tb >> 6;        // 64 k-blocks x 16 d-blocks
        const int k0 = kb * 64, d0 = db * 64;
        const int l16 = tid & 15, g16 = tid >> 4;    // 16 lanes x 16 groups
        #pragma unroll
        for (int i = 0; i < 4; ++i) {
            int r = i * 16 + g16;                    // d-row within tile
            float4 v = *(const float4*)&w[(size_t)(d0 + r) * Kn + k0 + l16 * 4];
            t[r][l16 * 4 + 0] = v.x; t[r][l16 * 4 + 1] = v.y;
            t[r][l16 * 4 + 2] = v.z; t[r][l16 * 4 + 3] = v.w;
        }
        __syncthreads();
        #pragma unroll
        for (int i = 0; i < 4; ++i) {
            int kr = i * 16 + g16;                   // k-row within tile
            float4 v;
            v.x = t[l16 * 4 + 0][kr]; v.y = t[l16 * 4 + 1][kr];
            v.z = t[l16 * 4 + 2][kr]; v.w = t[l16 * 4 + 3][kr];
            *(float4*)&wtf[(size_t)(k0 + kr) * Dn + d0 + l16 * 4] = v;
            int pk = pk_fp8_lo(v.x, v.y, 0); pk = pk_fp8_hi(v.z, v.w, pk);
            const int krow = k0 + kr;
            *(unsigned int*)&wf8[(size_t)krow * Dn + permoff(d0 + l16 * 4, krow)] =
                (unsigned int)pk;                    // bytes 0..3 = fp8(x,y,z,w)
        }
        // column-stat partial over this block's 64 d: sum (w^2 - 2 eps w)
        const int tx = tid & 63, ty = tid >> 6;
        float cs = 0.f;
        #pragma unroll
        for (int j = 0; j < 16; ++j) {
            float v = t[ty * 16 + j][tx];
            cs = fmaf(v, v - 2.f * EPS, cs);
        }
        cp[ty][tx] = cs;
        __syncthreads();
        if (ty == 0)
            cpart[(size_t)db * Kn + k0 + tx] = cp[0][tx] + cp[1][tx] + cp[2][tx] + cp[3][tx];
    }
}

// ---- MX-fp8 MFMA screen GEMM, DOUBLE-BUFFERED (T3-minimum 2-phase) -------
// Best-measured configuration (R10: 132.0 us total). Stage tile t+1 into
// buf^1 BEFORE computing buf t; one __syncthreads per iter (true compiler
// fence + full drain — the counted-vmcnt variant measured neutral and its
// A-direct extension was unsound). LDS 64 KB -> 2 blocks/CU.
__global__ __launch_bounds__(256, 2) void som_gemm_mx(
    const unsigned char* __restrict__ xf8, const unsigned char* __restrict__ wf8,
    const float* __restrict__ cpart, float* __restrict__ pval) {
    __shared__ __align__(16) unsigned char As[2][128 * 128];
    __shared__ __align__(16) unsigned char Bs[2][128 * 128];
    const int tid = threadIdx.x;
    const int lane = tid & 63;
    const int wid = tid >> 6;
    const int wm = wid >> 1, wn = wid & 1;    // 2x2 waves of 64x64
    const int f = blockIdx.x;
    const int xcd = f & 7;
    const int ib = f >> 3;
    const int rb = xcd * 4 + (ib & 3);
    const int cb = ib >> 2;
    const int rowBase = rb * 128, colBase = cb * 128;

    // staging: wave issue i covers rows [i*32 + wid*8, +8), lane l -> row
    // +(l>>3), byte (l&7)*16. LDS rows are verbatim copies of the permuted
    // global rows (linear dst = wave base + lane*16).
    const unsigned char* gA0 = xf8 + (size_t)(rowBase + wid * 8 + (lane >> 3)) * Dn + (lane & 7) * 16;
    const unsigned char* gB0 = wf8 + (size_t)(colBase + wid * 8 + (lane >> 3)) * Dn + (lane & 7) * 16;
    const int lOff = (wid * 8) * 128;

    f32x4 acc[4][4] = {};

    // fragment geometry: lane (row lane&15, quad q=lane>>4) reads its 32-B
    // fragment as two 16-B slots at XOR-decoded columns.
    const int arow = wm * 64 + (lane & 15);
    const int brow = wn * 64 + (lane & 15);
    const int q32 = (lane >> 4) * 32;
    const int aL = q32 ^ ((arow & 7) << 4), aH = (q32 + 16) ^ ((arow & 7) << 4);
    const int bL = q32 ^ ((brow & 7) << 4), bH = (q32 + 16) ^ ((brow & 7) << 4);

    #pragma unroll
    for (int i = 0; i < 4; ++i) {            // prologue: stage tile 0 -> buf 0
        gload16(gA0 + (size_t)i * 32 * Dn, &As[0][lOff + i * 32 * 128]);
        gload16(gB0 + (size_t)i * 32 * Dn, &Bs[0][lOff + i * 32 * 128]);
    }
    __syncthreads();                          // drains vmcnt -> buf 0 ready

    int cur = 0;
    for (int it = 0; it < 8; ++it) {
        if (it < 7) {                         // stage t+1 -> buf^1 FIRST:
            const int d0n = (it + 1) * 128;   // loads fly under the compute
            #pragma unroll
            for (int i = 0; i < 4; ++i) {
                gload16(gA0 + (size_t)i * 32 * Dn + d0n, &As[cur ^ 1][lOff + i * 32 * 128]);
                gload16(gB0 + (size_t)i * 32 * Dn + d0n, &Bs[cur ^ 1][lOff + i * 32 * 128]);
            }
        }
        const unsigned char* cA = As[cur];
        const unsigned char* cB = Bs[cur];
        i32x8 af[4];
        #pragma unroll
        for (int i = 0; i < 4; ++i) {
            i32x4 lo = *(const i32x4*)&cA[(arow + i * 16) * 128 + aL];
            i32x4 hi = *(const i32x4*)&cA[(arow + i * 16) * 128 + aH];
            af[i] = __builtin_shufflevector(lo, hi, 0, 1, 2, 3, 4, 5, 6, 7);
        }
        #pragma unroll
        for (int j = 0; j < 4; ++j) {
            i32x4 lo = *(const i32x4*)&cB[(brow + j * 16) * 128 + bL];
            i32x4 hi = *(const i32x4*)&cB[(brow + j * 16) * 128 + bH];
            i32x8 bf = __builtin_shufflevector(lo, hi, 0, 1, 2, 3, 4, 5, 6, 7);
            #pragma unroll
            for (int i = 0; i < 4; ++i)
                asm("v_mfma_f32_16x16x128_f8f6f4 %0, %1, %2, %0"
                    : "+v"(acc[i][j]) : "v"(af[i]), "v"(bf));
        }
        __syncthreads();                      // reads done + next buf landed
        cur ^= 1;
    }

    // epilogue: c[k] from cpart, then packed top-2 per (row, 64-col group)
    const int cn = lane & 15, q = lane >> 4;
    const int nbase = colBase + wn * 64;
    float cv[4];
    #pragma unroll
    for (int j = 0; j < 4; ++j) {
        float s = 0.f;
        #pragma unroll
        for (int db = 0; db < 16; ++db)
            s += cpart[(size_t)db * Kn + nbase + j * 16 + cn];
        cv[j] = s;
    }
    #pragma unroll
    for (int i = 0; i < 4; ++i) {
        #pragma unroll
        for (int rg = 0; rg < 4; ++rg) {
            float p1 = 3.4e38f, p2 = 3.4e38f;
            #pragma unroll
            for (int j = 0; j < 4; ++j) {
                float p = packcand(fmaf(-2.f, acc[i][j][rg], cv[j]),
                                   nbase + j * 16 + cn);
                float lo = fminf(p1, p), hi = fmaxf(p1, p);
                p1 = lo; p2 = fminf(p2, hi);
            }
            #pragma unroll
            for (int off = 1; off < 16; off <<= 1) {
                float o1 = __shfl_xor(p1, off);
                float o2 = __shfl_xor(p2, off);
                float lo = fminf(p1, o1), hi = fmaxf(p1, o1);
                p1 = lo; p2 = fminf(hi, fminf(p2, o2));
            }
            if (cn == 0) {
                int mrow = rowBase + wm * 64 + i * 16 + q * 4 + rg;
                size_t e = (size_t)mrow * 128 + cb * 4 + wn * 2;
                pval[e] = p1; pval[e + 1] = p2;
            }
        }
    }
}

// ---- finalize: exact fp32 rescore of candidates in margin (no atomics) ---
__global__ __launch_bounds__(256) void som_finalize(
    const float* __restrict__ x, const float* __restrict__ wtf,
    const float* __restrict__ cpart, const float* __restrict__ loc,
    const float* __restrict__ pval, const float* __restrict__ rrow,
    float* __restrict__ dist, float* __restrict__ out) {
    const int lane = threadIdx.x & 63;
    const int row = blockIdx.x * 4 + (threadIdx.x >> 6);

    const float4* xr = (const float4*)(x + (size_t)row * Dn);
    float4 xv[4];
    #pragma unroll
    for (int j = 0; j < 4; ++j) xv[j] = xr[lane * 4 + j];
    const float rrv = rrow[row];

    float v0 = pval[(size_t)row * 128 + lane];
    float v1 = pval[(size_t)row * 128 + 64 + lane];
    float g = fminf(v0, v1);
    #pragma unroll
    for (int off = 1; off < 64; off <<= 1) g = fminf(g, __shfl_xor(g, off));
    const float thr = g + 30.0f;  // fp8 screen noise (sigma~2.7) + pack error
    unsigned long long m0 = __ballot(v0 <= thr);
    unsigned long long m1 = __ballot(v1 <= thr);

    float bestd2 = 3.4e38f; int bestk = 0x7fffffff;
    #pragma unroll
    for (int slot = 0; slot < 2; ++slot) {
        unsigned long long m = slot ? m1 : m0;
        float vs = slot ? v1 : v0;
        while (m) {
            int src = __builtin_ctzll(m); m &= m - 1;
            int k = ((int)__float_as_uint(__shfl(vs, src))) & 0xFFF;
            const float4* wr = (const float4*)(wtf + (size_t)k * Dn);
            float pa = (lane < 16) ? cpart[(size_t)lane * Kn + k] : 0.f;
            float da = 0.f;
            #pragma unroll
            for (int j = 0; j < 4; ++j) {
                float4 wv = wr[lane * 4 + j];
                da += xv[j].x * wv.x + xv[j].y * wv.y + xv[j].z * wv.z + xv[j].w * wv.w;
            }
            pa -= 2.f * da;
            #pragma unroll
            for (int off = 1; off < 64; off <<= 1) pa += __shfl_xor(pa, off);
            float d2 = rrv + pa;
            if (d2 < bestd2 || (d2 == bestd2 && k < bestk)) { bestd2 = d2; bestk = k; }
        }
    }
    if (lane == 0) {
        out[2 * row]     = loc[2 * bestk];
        out[2 * row + 1] = loc[2 * bestk + 1];
        out[8193 + row]  = (float)bestk;
        dist[row]        = sqrtf(fmaxf(bestd2, 0.f));
    }
}

// ---- loss: single block reduces the 4096 per-row distances ----------------
__global__ __launch_bounds__(256) void som_loss(const float* __restrict__ dist,
                                                float* __restrict__ out) {
    __shared__ float red[4];
    const int tid = threadIdx.x;
    const int lane = tid & 63, wid = tid >> 6;
    const float4* p = (const float4*)dist;
    float s = 0.f;
    #pragma unroll
    for (int j = 0; j < 4; ++j) {
        float4 v = p[tid + j * 256];
        s += v.x + v.y + v.z + v.w;
    }
    #pragma unroll
    for (int off = 1; off < 64; off <<= 1) s += __shfl_xor(s, off);
    if (lane == 0) red[wid] = s;
    __syncthreads();
    if (tid == 0)
        out[8192] = (red[0] + red[1] + red[2] + red[3]) * (1.0f / (float)Bn);
}

extern "C" void kernel_launch(void* const* d_in, const int* in_sizes, int n_in,
                              void* d_out, int out_size, void* d_ws, size_t ws_size,
                              hipStream_t stream) {
    const float* x   = (const float*)d_in[0];   // [B, D]
    const float* w   = (const float*)d_in[1];   // [D, K]
    const float* loc = (const float*)d_in[2];   // [K, 2]
    float* out = (float*)d_out;

    float* rrow = (float*)d_ws;                            // 16 KB  [B]
    float* wtf  = rrow + Bn;                               // 16 MB  [K][D] fp32
    unsigned char* wf8 = (unsigned char*)(wtf + (size_t)Kn * Dn);  // 4 MB
    unsigned char* xf8 = wf8 + (size_t)Kn * Dn;            // 4 MB
    float* pval = (float*)(xf8 + (size_t)Bn * Dn);         // 2 MB packed top-2
    float* cpart = pval + (size_t)Bn * 128;                // 256 KB [16][K]
    float* dist  = cpart + 16 * Kn;                        // 16 KB  [B]

    som_prep<<<3072, 256, 0, stream>>>(x, w, xf8, rrow, wtf, wf8, cpart);
    som_gemm_mx<<<1024, 256, 0, stream>>>(xf8, wf8, cpart, pval);
    som_finalize<<<Bn / 4, 256, 0, stream>>>(x, wtf, cpart, loc, pval, rrow, dist, out);
    som_loss<<<1, 256, 0, stream>>>(dist, out);
}